// Round 15
// baseline (788.429 us; speedup 1.0000x reference)
//
#include <hip/hip_runtime.h>

// ---------------------------------------------------------------------------
// MHLP predictor — k_attn with FULL LDS weight staging (64 KB).
// R14 regression analysis: partial staging (Wq/Wk only) left Wv/opwT as ~32
// wave-uniform global dwordx4 loads per inner iteration; per-CU memory queue
// saturation (72 KB weights > 32 KB L1, perpetual L2 misses, ~60 loads in
// flight per wave x 12 waves) serialized the waves (VALUBusy 30%, HBM 1%).
// Fix: stage ipw(48KB)+opwT(16KB) = exactly 64 KB static LDS; ALL inner-loop
// weight reads are broadcast ds_read (conflict-free), zero global traffic in
// the hot loop. LDS -> 2 blocks/CU (8 waves/CU) but stall-free VALU issue.
// k_enc/k_pre unchanged from R14. Math identical: absmax must stay 2.441e-3.
// Predict: k_attn 527 -> 130-200 us, total ~320-400 us, VALUBusy 50-70%.
// ---------------------------------------------------------------------------

#define BTOT 262144

// d_ws float layout:
//   [0..256)        q0t[4][64]
//   [256..512)      k0t[4][64]
//   [512..768)      u0t[4][64]    (= out_proj_w . v0(hw))
//   [768..784)      s00t[4][4]    (raw q0.k0 per head, unscaled)
//   [1024..5120)    opwT[64][64]  (opwT[n][m] = opw[m][n])
//   [8192..16384)   W2T[128][64]  (W2T[j][n]  = W2[n][j])
//   [16384..)       arT4: float4 [16][BTOT]  (LN1 output, interleaved)
#define WS_OPWT 1024
#define WS_W2T  8192
#define WS_ART  16384

// ---------------- precompute: tables + transposes --------------------------
__global__ void k_pre(const float* __restrict__ hwe,
                      const float* __restrict__ ipw, const float* __restrict__ ipb,
                      const float* __restrict__ opw, const float* __restrict__ W2,
                      float* __restrict__ ws) {
  __shared__ float sq[256], sk[256], sv[256];
  const int t = threadIdx.x;          // 256 threads: r = t>>6 (hw row), n = t&63
  const int r = t >> 6, n = t & 63;
  const float* x = hwe + r * 64;
  float q = ipb[n], k = ipb[64 + n], v = ipb[128 + n];
#pragma unroll
  for (int j = 0; j < 64; ++j) {
    q += ipw[n * 64 + j] * x[j];
    k += ipw[(64 + n) * 64 + j] * x[j];
    v += ipw[(128 + n) * 64 + j] * x[j];
  }
  sq[t] = q; sk[t] = k; sv[t] = v;
  ws[t] = q; ws[256 + t] = k;
  __syncthreads();
  float u = 0.f;
#pragma unroll
  for (int j = 0; j < 64; ++j) u += opw[n * 64 + j] * sv[r * 64 + j];
  ws[512 + t] = u;
  if (t < 16) {
    const int rr = t >> 2, h = t & 3;
    float s = 0.f;
#pragma unroll
    for (int d = 0; d < 16; ++d)
      s += sq[rr * 64 + h * 16 + d] * sk[rr * 64 + h * 16 + d];
    ws[768 + t] = s;
  }
  // opwT[n][m] = opw[m][n]
  for (int i = t; i < 4096; i += 256) {
    const int nn = i >> 6, m = i & 63;
    ws[WS_OPWT + i] = opw[m * 64 + nn];
  }
  // W2T[j][n] = W2[n][j]
  for (int i = t; i < 8192; i += 256) {
    const int j = i >> 6, nn = i & 63;
    ws[WS_W2T + i] = W2[nn * 128 + j];
  }
}

// ---------------- K1: encoder -> arT4 (unchanged from R14) -----------------
__global__ __launch_bounds__(256) void k_enc(
    const int* __restrict__ g_op, const int* __restrict__ g_wd,
    const float* __restrict__ g_W1,  const float* __restrict__ g_b1,
    const float* __restrict__ g_b2,
    const float* __restrict__ g_ln1g, const float* __restrict__ g_ln1b,
    const float* __restrict__ ws) {
  __shared__ float sW2T[8192];   // 32 KB
  {
    const float4* src = (const float4*)(ws + WS_W2T);
    float4* dst = (float4*)sW2T;
#pragma unroll
    for (int c = 0; c < 8; ++c)
      dst[c * 256 + threadIdx.x] = src[c * 256 + threadIdx.x];
  }
  __syncthreads();

  const int i = blockIdx.x * 256 + threadIdx.x;

  const int c0 = g_op[i * 5 + 0] * 3 + g_wd[i * 5 + 0];
  const int c1 = 15 + g_op[i * 5 + 1] * 3 + g_wd[i * 5 + 1];
  const int c2 = 30 + g_op[i * 5 + 2] * 3 + g_wd[i * 5 + 2];
  const int c3 = 45 + g_op[i * 5 + 3] * 3 + g_wd[i * 5 + 3];
  const int c4 = 60 + g_op[i * 5 + 4] * 3 + g_wd[i * 5 + 4];

  float ar[64];
#pragma unroll
  for (int n = 0; n < 64; ++n) ar[n] = g_b2[n];

#pragma unroll 2
  for (int j = 0; j < 128; ++j) {
    const float* row = g_W1 + j * 75;
    float hj = g_b1[j] + row[c0] + row[c1] + row[c2] + row[c3] + row[c4];
    hj = hj > 0.f ? hj : 0.f;
    const float* w = sW2T + j * 64;
#pragma unroll
    for (int n = 0; n < 64; ++n) ar[n] += w[n] * hj;
  }

  float mean = 0.f;
#pragma unroll
  for (int n = 0; n < 64; ++n) mean += ar[n];
  mean *= (1.f / 64.f);
  float var = 0.f;
#pragma unroll
  for (int n = 0; n < 64; ++n) { const float d = ar[n] - mean; var += d * d; }
  var *= (1.f / 64.f);
  const float rstd = rsqrtf(var + 1e-5f);
#pragma unroll
  for (int n = 0; n < 64; ++n)
    ar[n] = (ar[n] - mean) * rstd * g_ln1g[n] + g_ln1b[n];

  float4* arT4 = (float4*)(ws + WS_ART);
#pragma unroll
  for (int k = 0; k < 16; ++k) {
    float4 v;
    v.x = ar[4 * k]; v.y = ar[4 * k + 1]; v.z = ar[4 * k + 2]; v.w = ar[4 * k + 3];
    arT4[(size_t)k * BTOT + i] = v;
  }
}

// ---------------- K2: attention + head -> out ------------------------------
__global__ __launch_bounds__(256) void k_attn(
    const int* __restrict__ g_hw,
    const float* __restrict__ g_hwe,
    const float* __restrict__ g_ipw, const float* __restrict__ g_ipb,
    const float* __restrict__ g_opb,
    const float* __restrict__ g_ln2g, const float* __restrict__ g_ln2b,
    const float* __restrict__ g_W3,  const float* __restrict__ g_b3,
    const float* __restrict__ g_W4,  const float* __restrict__ g_b4,
    const float* __restrict__ ws,
    float* __restrict__ g_out) {
  // 64 KB: ipw rows 0..191 (Wq,Wk,Wv) then opwT[64][64]
  __shared__ float sW[16384];
  {
    float4* dst = (float4*)sW;
    const float4* s1 = (const float4*)g_ipw;            // 3072 float4
#pragma unroll
    for (int c = 0; c < 12; ++c)
      dst[c * 256 + threadIdx.x] = s1[c * 256 + threadIdx.x];
    const float4* s2 = (const float4*)(ws + WS_OPWT);   // 1024 float4
#pragma unroll
    for (int c = 0; c < 4; ++c)
      dst[3072 + c * 256 + threadIdx.x] = s2[c * 256 + threadIdx.x];
  }
  __syncthreads();

  const int i = blockIdx.x * 256 + threadIdx.x;
  const int hw = g_hw[i];

  float ar[64];
  const float4* arT4 = (const float4*)(ws + WS_ART);
#pragma unroll
  for (int k = 0; k < 16; ++k) {
    const float4 v = arT4[(size_t)k * BTOT + i];
    ar[4 * k] = v.x; ar[4 * k + 1] = v.y; ar[4 * k + 2] = v.z; ar[4 * k + 3] = v.w;
  }

  const float* q0r = ws + hw * 64;
  const float* k0r = ws + 256 + hw * 64;
  const float* u0r = ws + 512 + hw * 64;

  float u1[64];
#pragma unroll
  for (int m = 0; m < 64; ++m) u1[m] = 0.f;

  float s01[4], s10[4], s11[4];
#pragma unroll
  for (int h = 0; h < 4; ++h) {
    float a01 = 0.f, a10 = 0.f, a11 = 0.f;
#pragma unroll 2
    for (int nn = 0; nn < 16; ++nn) {
      const int n = h * 16 + nn;
      const float* wq = sW + n * 64;            // LDS broadcast
      const float* wk = sW + (64 + n) * 64;     // LDS broadcast
      const float* wv = sW + (128 + n) * 64;    // LDS broadcast
      float q1 = g_ipb[n], k1 = g_ipb[64 + n], vv = g_ipb[128 + n];
#pragma unroll
      for (int j = 0; j < 64; ++j) {
        q1 += wq[j] * ar[j];
        k1 += wk[j] * ar[j];
        vv += wv[j] * ar[j];
      }
      const float q0n = q0r[n], k0n = k0r[n];
      a01 += q0n * k1;
      a10 += q1 * k0n;
      a11 += q1 * k1;
      const float* ot = sW + 12288 + n * 64;    // LDS broadcast
#pragma unroll
      for (int m = 0; m < 64; ++m) u1[m] += ot[m] * vv;
    }
    s01[h] = a01; s10[h] = a10; s11[h] = a11;
  }

  // softmax per head (scale 1/sqrt(16) = 0.25); s00 from table
  float a00[4], a01c[4], a10c[4], a11c[4];
#pragma unroll
  for (int h = 0; h < 4; ++h) {
    const float t00 = ws[768 + hw * 4 + h] * 0.25f;
    const float t01 = s01[h] * 0.25f;
    const float t10 = s10[h] * 0.25f;
    const float t11 = s11[h] * 0.25f;
    const float mA = fmaxf(t00, t01);
    const float e0 = __expf(t00 - mA), e1 = __expf(t01 - mA);
    const float iA = 1.f / (e0 + e1);
    a00[h] = e0 * iA; a01c[h] = e1 * iA;
    const float mB = fmaxf(t10, t11);
    const float f0 = __expf(t10 - mB), f1 = __expf(t11 - mB);
    const float iB = 1.f / (f0 + f1);
    a10c[h] = f0 * iB; a11c[h] = f1 * iB;
  }

  float pooled[64];
  // token1 first: t1 = opb + a10*u0 + a11*u1 + ar ; LN2
  {
    float t1[64];
    float mean = 0.f;
#pragma unroll
    for (int n = 0; n < 64; ++n) {
      const int h = n >> 4;
      const float s = g_opb[n] + a10c[h] * u0r[n] + a11c[h] * u1[n] + ar[n];
      t1[n] = s; mean += s;
    }
    mean *= (1.f / 64.f);
    float var = 0.f;
#pragma unroll
    for (int n = 0; n < 64; ++n) { const float d = t1[n] - mean; var += d * d; }
    var *= (1.f / 64.f);
    const float rstd = rsqrtf(var + 1e-5f);
#pragma unroll
    for (int n = 0; n < 64; ++n)
      pooled[n] = 0.5f * ((t1[n] - mean) * rstd * g_ln2g[n] + g_ln2b[n]);
  }
  // token0: t0 = opb + a00*u0 + a01*u1 + x0 ; LN2
  {
    const float* x0r = g_hwe + hw * 64;
    float t0[64];
    float mean = 0.f;
#pragma unroll
    for (int n = 0; n < 64; ++n) {
      const int h = n >> 4;
      const float s = g_opb[n] + a00[h] * u0r[n] + a01c[h] * u1[n] + x0r[n];
      t0[n] = s; mean += s;
    }
    mean *= (1.f / 64.f);
    float var = 0.f;
#pragma unroll
    for (int n = 0; n < 64; ++n) { const float d = t0[n] - mean; var += d * d; }
    var *= (1.f / 64.f);
    const float rstd = rsqrtf(var + 1e-5f);
#pragma unroll
    for (int n = 0; n < 64; ++n)
      pooled[n] += 0.5f * ((t0[n] - mean) * rstd * g_ln2g[n] + g_ln2b[n]);
  }

  // head: rolled over m, inner unrolled
  float acc = g_b4[0];
#pragma unroll 1
  for (int m = 0; m < 32; ++m) {
    const float* w = g_W3 + m * 64;
    float y = g_b3[m];
#pragma unroll
    for (int j = 0; j < 64; ++j) y += w[j] * pooled[j];
    y = y > 0.f ? y : 0.f;
    acc += y * g_W4[m];
  }
  g_out[i] = acc;
}

extern "C" void kernel_launch(void* const* d_in, const int* in_sizes, int n_in,
                              void* d_out, int out_size, void* d_ws, size_t ws_size,
                              hipStream_t stream) {
  (void)in_sizes; (void)n_in; (void)out_size; (void)ws_size;
  float* ws = (float*)d_ws;

  k_pre<<<1, 256, 0, stream>>>(
      (const float*)d_in[3], (const float*)d_in[10], (const float*)d_in[11],
      (const float*)d_in[12], (const float*)d_in[6], ws);

  k_enc<<<BTOT / 256, 256, 0, stream>>>(
      (const int*)d_in[1], (const int*)d_in[2],
      (const float*)d_in[4], (const float*)d_in[5],
      (const float*)d_in[7],
      (const float*)d_in[8], (const float*)d_in[9],
      ws);

  k_attn<<<BTOT / 256, 256, 0, stream>>>(
      (const int*)d_in[0],
      (const float*)d_in[3],
      (const float*)d_in[10], (const float*)d_in[11],
      (const float*)d_in[13],
      (const float*)d_in[14], (const float*)d_in[15],
      (const float*)d_in[16], (const float*)d_in[17],
      (const float*)d_in[18], (const float*)d_in[19],
      ws, (float*)d_out);
}

// Round 16
// 512.373 us; speedup vs baseline: 1.5388x; 1.5388x over previous
//
#include <hip/hip_runtime.h>

// ---------------------------------------------------------------------------
// MHLP predictor — CORRECTNESS-RESTORED attention + dual outer-product form.
// R12-R15 carried a real math bug: out_proj applied as a*(opw.v0)+a'*(opw.v1)
// with softmax coefs indexed by OUTPUT head — wrong, since coefs vary per
// value-dim head inside the contraction (absmax jumped 2.44e-4 -> 2.44e-3;
// passed only by init luck). Fix: per value-dim d, ctx0_d = a01[h(d)]*v1_d
// (+v0 part via exact per-(hw,head) table u0h = opw.(e_h o v0)), accumulated
// as DUAL outer products into t0[64], t1[64] — each opw column read drives
// 128 independent FMAs (2x load amortization, deep ILP for latency hiding).
// Weights stream on the R13-measured-best global/SMEM path (LDS staging
// regressed twice: R14 527, R15 673 vs R13 460 — latency, not bandwidth).
// Predict: absmax back to ~2.44e-4; k_attn 350-550 us; total 500-700 us.
// ---------------------------------------------------------------------------

#define BTOT 262144

// d_ws float layout:
//   [0..256)        q0t[4][64]
//   [256..512)      k0t[4][64]
//   [768..784)      s00t[4][4]     (raw q0.k0 per head, unscaled)
//   [1024..5120)    opwT[64][64]   (opwT[d][m] = opw[m][d])
//   [5120..6144)    u0h[4 hw][4 h][64 m] = sum_{d in h} opw[m][d]*v0[d]
//   [8192..16384)   W2T[128][64]   (W2T[j][n] = W2[n][j])
//   [16384..)       arT4: float4 [16][BTOT]
#define WS_OPWT 1024
#define WS_U0H  5120
#define WS_W2T  8192
#define WS_ART  16384

// ---------------- precompute: tables + transposes --------------------------
__global__ void k_pre(const float* __restrict__ hwe,
                      const float* __restrict__ ipw, const float* __restrict__ ipb,
                      const float* __restrict__ opw, const float* __restrict__ W2,
                      float* __restrict__ ws) {
  __shared__ float sq[256], sk[256], sv[256];
  const int t = threadIdx.x;          // r = t>>6 (hw row), n = t&63
  const int r = t >> 6, n = t & 63;
  const float* x = hwe + r * 64;
  float q = ipb[n], k = ipb[64 + n], v = ipb[128 + n];
#pragma unroll
  for (int j = 0; j < 64; ++j) {
    q += ipw[n * 64 + j] * x[j];
    k += ipw[(64 + n) * 64 + j] * x[j];
    v += ipw[(128 + n) * 64 + j] * x[j];
  }
  sq[t] = q; sk[t] = k; sv[t] = v;
  ws[t] = q; ws[256 + t] = k;
  __syncthreads();
  // u0h[r][h][n] = sum_{d in head h} opw[n][d] * v0_r[d]
#pragma unroll
  for (int h = 0; h < 4; ++h) {
    float u = 0.f;
#pragma unroll
    for (int dd = 0; dd < 16; ++dd) {
      const int d = h * 16 + dd;
      u += opw[n * 64 + d] * sv[r * 64 + d];
    }
    ws[WS_U0H + r * 256 + h * 64 + n] = u;
  }
  if (t < 16) {
    const int rr = t >> 2, h = t & 3;
    float s = 0.f;
#pragma unroll
    for (int d = 0; d < 16; ++d)
      s += sq[rr * 64 + h * 16 + d] * sk[rr * 64 + h * 16 + d];
    ws[768 + t] = s;
  }
  // opwT[d][m] = opw[m][d]
  for (int i = t; i < 4096; i += 256) {
    const int d = i >> 6, m = i & 63;
    ws[WS_OPWT + i] = opw[m * 64 + d];
  }
  // W2T[j][n] = W2[n][j]
  for (int i = t; i < 8192; i += 256) {
    const int j = i >> 6, nn = i & 63;
    ws[WS_W2T + i] = W2[nn * 128 + j];
  }
}

// ---------------- K1: encoder -> arT4 (R15 form, LDS W2T) ------------------
__global__ __launch_bounds__(256) void k_enc(
    const int* __restrict__ g_op, const int* __restrict__ g_wd,
    const float* __restrict__ g_W1,  const float* __restrict__ g_b1,
    const float* __restrict__ g_b2,
    const float* __restrict__ g_ln1g, const float* __restrict__ g_ln1b,
    const float* __restrict__ ws) {
  __shared__ float sW2T[8192];   // 32 KB
  {
    const float4* src = (const float4*)(ws + WS_W2T);
    float4* dst = (float4*)sW2T;
#pragma unroll
    for (int c = 0; c < 8; ++c)
      dst[c * 256 + threadIdx.x] = src[c * 256 + threadIdx.x];
  }
  __syncthreads();

  const int i = blockIdx.x * 256 + threadIdx.x;

  const int c0 = g_op[i * 5 + 0] * 3 + g_wd[i * 5 + 0];
  const int c1 = 15 + g_op[i * 5 + 1] * 3 + g_wd[i * 5 + 1];
  const int c2 = 30 + g_op[i * 5 + 2] * 3 + g_wd[i * 5 + 2];
  const int c3 = 45 + g_op[i * 5 + 3] * 3 + g_wd[i * 5 + 3];
  const int c4 = 60 + g_op[i * 5 + 4] * 3 + g_wd[i * 5 + 4];

  float ar[64];
#pragma unroll
  for (int n = 0; n < 64; ++n) ar[n] = g_b2[n];

#pragma unroll 2
  for (int j = 0; j < 128; ++j) {
    const float* row = g_W1 + j * 75;
    float hj = g_b1[j] + row[c0] + row[c1] + row[c2] + row[c3] + row[c4];
    hj = hj > 0.f ? hj : 0.f;
    const float* w = sW2T + j * 64;
#pragma unroll
    for (int n = 0; n < 64; ++n) ar[n] += w[n] * hj;
  }

  float mean = 0.f;
#pragma unroll
  for (int n = 0; n < 64; ++n) mean += ar[n];
  mean *= (1.f / 64.f);
  float var = 0.f;
#pragma unroll
  for (int n = 0; n < 64; ++n) { const float d = ar[n] - mean; var += d * d; }
  var *= (1.f / 64.f);
  const float rstd = rsqrtf(var + 1e-5f);
#pragma unroll
  for (int n = 0; n < 64; ++n)
    ar[n] = (ar[n] - mean) * rstd * g_ln1g[n] + g_ln1b[n];

  float4* arT4 = (float4*)(ws + WS_ART);
#pragma unroll
  for (int k = 0; k < 16; ++k) {
    float4 v;
    v.x = ar[4 * k]; v.y = ar[4 * k + 1]; v.z = ar[4 * k + 2]; v.w = ar[4 * k + 3];
    arT4[(size_t)k * BTOT + i] = v;
  }
}

// ---------------- K2: attention + head (correct math) ----------------------
__global__ __launch_bounds__(256, 2) void k_attn(
    const int* __restrict__ g_hw,
    const float* __restrict__ g_hwe,
    const float* __restrict__ g_ipw, const float* __restrict__ g_ipb,
    const float* __restrict__ g_opb,
    const float* __restrict__ g_ln2g, const float* __restrict__ g_ln2b,
    const float* __restrict__ g_W3,  const float* __restrict__ g_b3,
    const float* __restrict__ g_W4,  const float* __restrict__ g_b4,
    const float* __restrict__ ws,
    float* __restrict__ g_out) {
  const int i = blockIdx.x * 256 + threadIdx.x;
  const int hw = g_hw[i];

  float ar[64];
  const float4* arT4 = (const float4*)(ws + WS_ART);
#pragma unroll
  for (int k = 0; k < 16; ++k) {
    const float4 v = arT4[(size_t)k * BTOT + i];
    ar[4 * k] = v.x; ar[4 * k + 1] = v.y; ar[4 * k + 2] = v.z; ar[4 * k + 3] = v.w;
  }

  const float* q0r = ws + hw * 64;
  const float* k0r = ws + 256 + hw * 64;

  // ---- pass 1: scores (q,k rows streamed from global/SMEM) ----
  float s01[4], s10[4], s11[4];
#pragma unroll
  for (int h = 0; h < 4; ++h) {
    float a01 = 0.f, a10 = 0.f, a11 = 0.f;
#pragma unroll 2
    for (int nn = 0; nn < 16; ++nn) {
      const int n = h * 16 + nn;
      const float* wq = g_ipw + n * 64;
      const float* wk = g_ipw + (64 + n) * 64;
      float q1 = g_ipb[n], k1 = g_ipb[64 + n];
#pragma unroll
      for (int j = 0; j < 64; ++j) {
        q1 += wq[j] * ar[j];
        k1 += wk[j] * ar[j];
      }
      a01 += q0r[n] * k1;
      a10 += q1 * k0r[n];
      a11 += q1 * k1;
    }
    s01[h] = a01; s10[h] = a10; s11[h] = a11;
  }

  // ---- softmax per head (scale 1/sqrt(16) = 0.25); s00 from table ----
  float a00[4], a01c[4], a10c[4], a11c[4];
#pragma unroll
  for (int h = 0; h < 4; ++h) {
    const float t00 = ws[768 + hw * 4 + h] * 0.25f;
    const float t01 = s01[h] * 0.25f;
    const float t10 = s10[h] * 0.25f;
    const float t11 = s11[h] * 0.25f;
    const float mA = fmaxf(t00, t01);
    const float e0 = __expf(t00 - mA), e1 = __expf(t01 - mA);
    const float iA = 1.f / (e0 + e1);
    a00[h] = e0 * iA; a01c[h] = e1 * iA;
    const float mB = fmaxf(t10, t11);
    const float f0 = __expf(t10 - mB), f1 = __expf(t11 - mB);
    const float iB = 1.f / (f0 + f1);
    a10c[h] = f0 * iB; a11c[h] = f1 * iB;
  }

  // ---- pass 2: v1 stream + DUAL outer product (correct per-head ctx) ----
  float t0[64], t1[64];
#pragma unroll
  for (int m = 0; m < 64; ++m) { t0[m] = 0.f; t1[m] = 0.f; }
#pragma unroll
  for (int h = 0; h < 4; ++h) {
#pragma unroll 1
    for (int nn = 0; nn < 16; ++nn) {
      const int d = h * 16 + nn;
      const float* wv = g_ipw + (128 + d) * 64;
      float vv = g_ipb[128 + d];
#pragma unroll
      for (int j = 0; j < 64; ++j) vv += wv[j] * ar[j];
      const float c0 = a01c[h] * vv;    // ctx0_d v1-part
      const float c1 = a11c[h] * vv;    // ctx1_d v1-part
      const float* ot = ws + WS_OPWT + d * 64;  // opw[:,d]
#pragma unroll
      for (int m = 0; m < 64; ++m) {
        const float o = ot[m];
        t0[m] += o * c0;
        t1[m] += o * c1;
      }
    }
  }
  // v0 parts via exact per-(hw,head) table
  {
    const float* uh = ws + WS_U0H + hw * 256;
#pragma unroll
    for (int h = 0; h < 4; ++h) {
      const float* u = uh + h * 64;
      const float ca = a00[h], cb = a10c[h];
#pragma unroll
      for (int m = 0; m < 64; ++m) {
        const float o = u[m];
        t0[m] += o * ca;
        t1[m] += o * cb;
      }
    }
  }

  // ---- bias + residual ----
  {
    const float* x0r = g_hwe + hw * 64;
#pragma unroll
    for (int m = 0; m < 64; ++m) {
      const float b = g_opb[m];
      t0[m] += b + x0r[m];
      t1[m] += b + ar[m];
    }
  }

  // ---- LN2 each token; pooled accumulated in-place into t1 ----
  {
    float mean = 0.f;
#pragma unroll
    for (int n = 0; n < 64; ++n) mean += t1[n];
    mean *= (1.f / 64.f);
    float var = 0.f;
#pragma unroll
    for (int n = 0; n < 64; ++n) { const float d = t1[n] - mean; var += d * d; }
    var *= (1.f / 64.f);
    const float rstd = rsqrtf(var + 1e-5f);
#pragma unroll
    for (int n = 0; n < 64; ++n)
      t1[n] = 0.5f * ((t1[n] - mean) * rstd * g_ln2g[n] + g_ln2b[n]);
  }
  {
    float mean = 0.f;
#pragma unroll
    for (int n = 0; n < 64; ++n) mean += t0[n];
    mean *= (1.f / 64.f);
    float var = 0.f;
#pragma unroll
    for (int n = 0; n < 64; ++n) { const float d = t0[n] - mean; var += d * d; }
    var *= (1.f / 64.f);
    const float rstd = rsqrtf(var + 1e-5f);
#pragma unroll
    for (int n = 0; n < 64; ++n)
      t1[n] += 0.5f * ((t0[n] - mean) * rstd * g_ln2g[n] + g_ln2b[n]);
  }

  // ---- head: relu(pooled @ W3^T + b3) . W4 + b4  (pooled == t1) ----
  float acc = g_b4[0];
#pragma unroll 1
  for (int m = 0; m < 32; ++m) {
    const float* w = g_W3 + m * 64;
    float y = g_b3[m];
#pragma unroll
    for (int j = 0; j < 64; ++j) y += w[j] * t1[j];
    y = y > 0.f ? y : 0.f;
    acc += y * g_W4[m];
  }
  g_out[i] = acc;
}

extern "C" void kernel_launch(void* const* d_in, const int* in_sizes, int n_in,
                              void* d_out, int out_size, void* d_ws, size_t ws_size,
                              hipStream_t stream) {
  (void)in_sizes; (void)n_in; (void)out_size; (void)ws_size;
  float* ws = (float*)d_ws;

  k_pre<<<1, 256, 0, stream>>>(
      (const float*)d_in[3], (const float*)d_in[10], (const float*)d_in[11],
      (const float*)d_in[12], (const float*)d_in[6], ws);

  k_enc<<<BTOT / 256, 256, 0, stream>>>(
      (const int*)d_in[1], (const int*)d_in[2],
      (const float*)d_in[4], (const float*)d_in[5],
      (const float*)d_in[7],
      (const float*)d_in[8], (const float*)d_in[9],
      ws);

  k_attn<<<BTOT / 256, 256, 0, stream>>>(
      (const int*)d_in[0],
      (const float*)d_in[3],
      (const float*)d_in[10], (const float*)d_in[11],
      (const float*)d_in[13],
      (const float*)d_in[14], (const float*)d_in[15],
      (const float*)d_in[16], (const float*)d_in[17],
      (const float*)d_in[18], (const float*)d_in[19],
      ws, (float*)d_out);
}

// Round 17
// 256.451 us; speedup vs baseline: 3.0744x; 1.9979x over previous
//
#include <hip/hip_runtime.h>

// ---------------------------------------------------------------------------
// MHLP predictor — f16 MFMA version (per-wave 16-sample tiles).
// R16 proved correct math at 512 us, scalar-VALU-bound (~3x from its own
// floor; f32 network floor ~146 us). This round moves the matmuls to
// v_mfma_f32_16x16x32_f16 (fp32 accum; fp16 err 2^-11 keeps absmax ~1e-3):
//   k_pre : swizzle all weights into B-frag layout (f16) in d_ws
//   k_enc : onehot->W1->relu->W2->LN1 -> arch[B][64] f16  (24+16 MFMA/tile)
//   k_attn: qkv->attention->out_proj->LN2->pool->head     (48+16+4 MFMA/tile)
// Frag layouts (m89/m91/m120-verified, dtype-independent m121-128):
//   A[m=lane&15][k=(lane>>4)*8+j]; B-frag[lane][j]=W[nt*16+(lane&15)]
//   [ks*32+(lane>>4)*8+j]; C/D: col=lane&15, row=(lane>>4)*4+reg.
// Static LDS: k_enc 59392 B, k_attn 63104 B (<=64 KB, R2-proven shape).
// Predict: 512 -> 120-220 us; MfmaUtil first nonzero; absmax ~1e-3.
// ---------------------------------------------------------------------------

using s8v = __attribute__((ext_vector_type(8))) short;
using h8  = __attribute__((ext_vector_type(8))) _Float16;
using f4  = __attribute__((ext_vector_type(4))) float;

#define BTOT 262144

// d_ws u16-unit layout (pre-swizzled f16 weight frags + arch)
#define WF_W1   0        // 12288  (K=75->KS=3, NT=8)
#define WF_W2   12288    // 8192   (K=128->KS=4, NT=4)
#define WF_IP   20480    // 12288  (K=64->KS=2, NT=12)
#define WF_OP   32768    // 4096   (K=64->KS=2, NT=4)
#define WF_W3   36864    // 2048   (K=64->KS=2, NT=2)
#define WF_HWE  38912    // 256    (hw_embed f16 [4][64])
#define WF_ARCH 65536    // BTOT*64 arch f16

__device__ __forceinline__ unsigned short f2h(float f) {
  _Float16 h = (_Float16)f;
  return __builtin_bit_cast(unsigned short, h);
}
__device__ __forceinline__ float h2f(unsigned short u) {
  return (float)__builtin_bit_cast(_Float16, u);
}

__device__ __forceinline__ void swz(const float* __restrict__ W,
                                    unsigned short* __restrict__ dst,
                                    int Kreal, int KS, int NT, int t) {
  const int total = KS * NT * 512;
  for (int i = t; i < total; i += 256) {
    const int j = i & 7, ln = (i >> 3) & 63, fr = i >> 9;
    const int nt = fr % NT, ks = fr / NT;
    const int n = nt * 16 + (ln & 15);
    const int k = ks * 32 + (ln >> 4) * 8 + j;
    dst[i] = (k < Kreal) ? f2h(W[n * Kreal + k]) : (unsigned short)0;
  }
}

__global__ void k_pre(const float* __restrict__ hwe,
                      const float* __restrict__ W1, const float* __restrict__ W2,
                      const float* __restrict__ ipw, const float* __restrict__ opw,
                      const float* __restrict__ W3,
                      unsigned short* __restrict__ ws) {
  const int t = threadIdx.x;
  swz(W1,  ws + WF_W1, 75, 3, 8, t);
  swz(W2,  ws + WF_W2, 128, 4, 4, t);
  swz(ipw, ws + WF_IP, 64, 2, 12, t);
  swz(opw, ws + WF_OP, 64, 2, 4, t);
  swz(W3,  ws + WF_W3, 64, 2, 2, t);
  for (int i = t; i < 256; i += 256) ws[WF_HWE + i] = f2h(hwe[i]);
}

// ===================== K1: encoder -> arch[B][64] f16 ======================
// LDS u16: W1 frags 0..12288, W2 12288..20480, per-wave 20480 + w*2304
//   per-wave: h [16][136]@0 (arch [16][72] reuses front), targ [16][8]@2176
#define K1_PW  20480
#define K1_PWS 2304
#define K1_TOT 29696   // 59392 B

__global__ __launch_bounds__(256) void k_enc(
    const int* __restrict__ g_op, const int* __restrict__ g_wd,
    const float* __restrict__ g_b1, const float* __restrict__ g_b2,
    const float* __restrict__ g_ln1g, const float* __restrict__ g_ln1b,
    const unsigned short* __restrict__ wsf, unsigned short* __restrict__ g_arch) {
  __shared__ __align__(16) unsigned short sm[K1_TOT];
  const int tid = threadIdx.x;
  {
    const float4* src = (const float4*)wsf;       // frags at WF_W1=0
    float4* dst = (float4*)sm;
    for (int c = tid; c < 2560; c += 256) dst[c] = src[c];
  }
  __syncthreads();

  const int wave = tid >> 6, lane = tid & 63;
  const int quad = lane >> 4, l15 = lane & 15;
  unsigned short* pw = sm + K1_PW + wave * K1_PWS;
  const int gwave = blockIdx.x * 4 + wave;        // 0..2047

  for (int t = 0; t < 8; ++t) {
    const int m0 = (t * 2048 + gwave) * 16;

    if (lane < 16) {
      const int smp = m0 + lane;
#pragma unroll
      for (int l = 0; l < 5; ++l) {
        const int c = 15 * l + g_op[smp * 5 + l] * 3 + g_wd[smp * 5 + l];
        pw[2176 + lane * 8 + l] = (unsigned short)c;
      }
      pw[2176 + lane * 8 + 5] = 0xFFFFu;
      pw[2176 + lane * 8 + 6] = 0xFFFFu;
      pw[2176 + lane * 8 + 7] = 0xFFFFu;
    }
    const s8v trow = *(const s8v*)(pw + 2176 + l15 * 8);

    h8 aoh[3];
#pragma unroll
    for (int ks = 0; ks < 3; ++ks) {
      s8v a;
#pragma unroll
      for (int j = 0; j < 8; ++j) {
        const int k = ks * 32 + quad * 8 + j;
        bool hit = false;
#pragma unroll
        for (int l = 0; l < 5; ++l)
          hit = hit || (k == (int)(unsigned short)trow[l]);
        a[j] = hit ? (short)0x3C00 : (short)0;   // f16 1.0
      }
      aoh[ks] = __builtin_bit_cast(h8, a);
    }

    // S1: h = relu(onehot @ W1^T + b1) -> pw[0..2176] stride 136 (f16)
#pragma unroll
    for (int nt = 0; nt < 8; ++nt) {
      f4 acc = {0.f, 0.f, 0.f, 0.f};
#pragma unroll
      for (int ks = 0; ks < 3; ++ks) {
        const h8 bf = *(const h8*)(sm + ((ks * 8 + nt) * 64 + lane) * 8);
        acc = __builtin_amdgcn_mfma_f32_16x16x32_f16(aoh[ks], bf, acc, 0, 0, 0);
      }
      const int col = nt * 16 + l15;
      const float bias = g_b1[col];
#pragma unroll
      for (int r = 0; r < 4; ++r) {
        float v = acc[r] + bias;
        v = v > 0.f ? v : 0.f;
        pw[(quad * 4 + r) * 136 + col] = f2h(v);
      }
    }

    // S2: arch = LN1(h @ W2^T + b2) -> pw[0..1152] stride 72
    h8 a2[4];
#pragma unroll
    for (int ks = 0; ks < 4; ++ks)
      a2[ks] = *(const h8*)(pw + l15 * 136 + ks * 32 + quad * 8);
    f4 acc2[4];
#pragma unroll
    for (int nt = 0; nt < 4; ++nt) {
      f4 acc = {0.f, 0.f, 0.f, 0.f};
#pragma unroll
      for (int ks = 0; ks < 4; ++ks) {
        const h8 bf = *(const h8*)(sm + 12288 + ((ks * 4 + nt) * 64 + lane) * 8);
        acc = __builtin_amdgcn_mfma_f32_16x16x32_f16(a2[ks], bf, acc, 0, 0, 0);
      }
      acc2[nt] = acc;
    }
    {
      float val[4][4];
#pragma unroll
      for (int nt = 0; nt < 4; ++nt) {
        const float bias = g_b2[nt * 16 + l15];
#pragma unroll
        for (int r = 0; r < 4; ++r) val[nt][r] = acc2[nt][r] + bias;
      }
#pragma unroll
      for (int r = 0; r < 4; ++r) {
        float s = val[0][r] + val[1][r] + val[2][r] + val[3][r];
        float q = val[0][r] * val[0][r] + val[1][r] * val[1][r] +
                  val[2][r] * val[2][r] + val[3][r] * val[3][r];
#pragma unroll
        for (int off = 1; off <= 8; off <<= 1) {
          s += __shfl_xor(s, off);
          q += __shfl_xor(q, off);
        }
        const float mean = s * (1.f / 64.f);
        const float var  = q * (1.f / 64.f) - mean * mean;
        const float rstd = rsqrtf(var + 1e-5f);
#pragma unroll
        for (int nt = 0; nt < 4; ++nt) {
          const int col = nt * 16 + l15;
          const float gg = g_ln1g[col], bb = g_ln1b[col];
          pw[(quad * 4 + r) * 72 + col] = f2h((val[nt][r] - mean) * rstd * gg + bb);
        }
      }
    }

    // cooperative store arch tile [16][64] f16 -> g_arch
#pragma unroll
    for (int o = 0; o < 2; ++o) {
      const int c = o * 64 + lane;
      const int row = c >> 3, coloff = (c & 7) * 8;
      const s8v v = *(const s8v*)(pw + row * 72 + coloff);
      *(s8v*)(g_arch + (size_t)(m0 + row) * 64 + coloff) = v;
    }
  }
}

// ===================== K2: attention + head -> out =========================
// LDS u16: IP 0..12288, OP 12288..16384, W3 16384..18432, HWE 18432..18688,
// per-wave 18688 + w*6432:
//   qkv [32][200]@0; ctx [32][72]@0 overlay; pooled [16][72]@2304;
//   archt [16][72]@3456; hwi@6400(16)
#define K2_PW  18688
#define K2_PWS 6432
#define K2_TOT 31552   // 63104 B

__global__ __launch_bounds__(128) void k_attn(
    const int* __restrict__ g_hw,
    const float* __restrict__ g_hwe,
    const float* __restrict__ g_ipb, const float* __restrict__ g_opb,
    const float* __restrict__ g_ln2g, const float* __restrict__ g_ln2b,
    const float* __restrict__ g_b3,  const float* __restrict__ g_W4,
    const float* __restrict__ g_b4,
    const unsigned short* __restrict__ wsf,   // d_ws base (u16)
    float* __restrict__ g_out) {
  __shared__ __align__(16) unsigned short sm[K2_TOT];
  const int tid = threadIdx.x;
  {
    const float4* src = (const float4*)(wsf + WF_IP);  // IP,OP,W3,HWE contiguous
    float4* dst = (float4*)sm;
    for (int c = tid; c < 2336; c += 128) dst[c] = src[c];
  }
  __syncthreads();

  const unsigned short* g_arch = wsf + WF_ARCH;
  const int wave = tid >> 6, lane = tid & 63;
  const int quad = lane >> 4, l15 = lane & 15;
  unsigned short* pw = sm + K2_PW + wave * K2_PWS;
  const int gwave = blockIdx.x * 2 + wave;            // 0..2047

  for (int t = 0; t < 8; ++t) {
    const int m0 = (t * 2048 + gwave) * 16;

    if (lane < 16) pw[6400 + lane] = (unsigned short)g_hw[m0 + lane];

    // S3: qkv = [hw_emb; arch] @ in_proj^T + ipb -> qkv[32][200] f16
    const int hwrow = (int)pw[6400 + l15];
    h8 at0[2], at1[2];
#pragma unroll
    for (int ks = 0; ks < 2; ++ks) {
      at0[ks] = *(const h8*)(sm + 18432 + hwrow * 64 + ks * 32 + quad * 8);
      at1[ks] = *(const h8*)(g_arch + (size_t)(m0 + l15) * 64 + ks * 32 + quad * 8);
    }
#pragma unroll
    for (int nt = 0; nt < 12; ++nt) {
      const h8 bf0 = *(const h8*)(sm + ((0 * 12 + nt) * 64 + lane) * 8);
      const h8 bf1 = *(const h8*)(sm + ((1 * 12 + nt) * 64 + lane) * 8);
      f4 a0 = {0.f, 0.f, 0.f, 0.f}, a1 = {0.f, 0.f, 0.f, 0.f};
      a0 = __builtin_amdgcn_mfma_f32_16x16x32_f16(at0[0], bf0, a0, 0, 0, 0);
      a0 = __builtin_amdgcn_mfma_f32_16x16x32_f16(at0[1], bf1, a0, 0, 0, 0);
      a1 = __builtin_amdgcn_mfma_f32_16x16x32_f16(at1[0], bf0, a1, 0, 0, 0);
      a1 = __builtin_amdgcn_mfma_f32_16x16x32_f16(at1[1], bf1, a1, 0, 0, 0);
      const int col = nt * 16 + l15;
      const float bias = g_ipb[col];
#pragma unroll
      for (int r = 0; r < 4; ++r) {
        pw[(quad * 4 + r) * 200 + col]      = f2h(a0[r] + bias);
        pw[(16 + quad * 4 + r) * 200 + col] = f2h(a1[r] + bias);
      }
    }

    // S4: attention per (sample=l15, head=quad); s00 computed exactly here
    float ctx[2][16];
    {
      float qv[2][16], kv[2][16], vv[2][16];
#pragma unroll
      for (int tt = 0; tt < 2; ++tt) {
        const unsigned short* base = pw + (tt * 16 + l15) * 200;
#pragma unroll
        for (int c = 0; c < 2; ++c) {
          const h8 qq = *(const h8*)(base + quad * 16 + c * 8);
          const h8 kk = *(const h8*)(base + 64 + quad * 16 + c * 8);
          const h8 vvv = *(const h8*)(base + 128 + quad * 16 + c * 8);
#pragma unroll
          for (int d = 0; d < 8; ++d) {
            qv[tt][c * 8 + d] = (float)qq[d];
            kv[tt][c * 8 + d] = (float)kk[d];
            vv[tt][c * 8 + d] = (float)vvv[d];
          }
        }
      }
      float s00 = 0.f, s01 = 0.f, s10 = 0.f, s11 = 0.f;
#pragma unroll
      for (int d = 0; d < 16; ++d) {
        s00 += qv[0][d] * kv[0][d];
        s01 += qv[0][d] * kv[1][d];
        s10 += qv[1][d] * kv[0][d];
        s11 += qv[1][d] * kv[1][d];
      }
      s00 *= 0.25f; s01 *= 0.25f; s10 *= 0.25f; s11 *= 0.25f;
      const float mA = fmaxf(s00, s01);
      const float e0 = __expf(s00 - mA), e1 = __expf(s01 - mA);
      const float iA = 1.f / (e0 + e1);
      const float a00 = e0 * iA, a01 = e1 * iA;
      const float mB = fmaxf(s10, s11);
      const float f0 = __expf(s10 - mB), f1 = __expf(s11 - mB);
      const float iB = 1.f / (f0 + f1);
      const float a10 = f0 * iB, a11 = f1 * iB;
#pragma unroll
      for (int d = 0; d < 16; ++d) {
        ctx[0][d] = a00 * vv[0][d] + a01 * vv[1][d];
        ctx[1][d] = a10 * vv[0][d] + a11 * vv[1][d];
      }
    }
#pragma unroll
    for (int tt = 0; tt < 2; ++tt)
#pragma unroll
      for (int d = 0; d < 16; d += 2) {
        const unsigned pk = (unsigned)f2h(ctx[tt][d]) |
                            ((unsigned)f2h(ctx[tt][d + 1]) << 16);
        *(unsigned*)(pw + (tt * 16 + l15) * 72 + quad * 16 + d) = pk;
      }

    // stage arch tile (residual) -> archt@3456 (qkv rows dead)
#pragma unroll
    for (int o = 0; o < 2; ++o) {
      const int c = o * 64 + lane;
      const int row = c >> 3, coloff = (c & 7) * 8;
      const s8v v = *(const s8v*)(g_arch + (size_t)(m0 + row) * 64 + coloff);
      *(s8v*)(pw + 3456 + row * 72 + coloff) = v;
    }

    // S5: out_proj + residual + LN2 + mean-pool -> pooled[16][72]@2304
    h8 ca[2][2];
#pragma unroll
    for (int mt = 0; mt < 2; ++mt)
#pragma unroll
      for (int ks = 0; ks < 2; ++ks)
        ca[mt][ks] = *(const h8*)(pw + (mt * 16 + l15) * 72 + ks * 32 + quad * 8);
    f4 oacc[2][4];
#pragma unroll
    for (int nt = 0; nt < 4; ++nt) {
      const h8 bf0 = *(const h8*)(sm + 12288 + ((0 * 4 + nt) * 64 + lane) * 8);
      const h8 bf1 = *(const h8*)(sm + 12288 + ((1 * 4 + nt) * 64 + lane) * 8);
#pragma unroll
      for (int mt = 0; mt < 2; ++mt) {
        f4 acc = {0.f, 0.f, 0.f, 0.f};
        acc = __builtin_amdgcn_mfma_f32_16x16x32_f16(ca[mt][0], bf0, acc, 0, 0, 0);
        acc = __builtin_amdgcn_mfma_f32_16x16x32_f16(ca[mt][1], bf1, acc, 0, 0, 0);
        oacc[mt][nt] = acc;
      }
    }
    float pool[4][4];
#pragma unroll
    for (int mt = 0; mt < 2; ++mt) {
      float val[4][4];
#pragma unroll
      for (int nt = 0; nt < 4; ++nt) {
        const int col = nt * 16 + l15;
        const float bias = g_opb[col];
#pragma unroll
        for (int r = 0; r < 4; ++r) {
          const int row = quad * 4 + r;
          float res;
          if (mt == 0) {
            const int hr = (int)pw[6400 + row];
            res = g_hwe[hr * 64 + col];
          } else {
            res = h2f(pw[3456 + row * 72 + col]);
          }
          val[nt][r] = oacc[mt][nt][r] + bias + res;
        }
      }
#pragma unroll
      for (int r = 0; r < 4; ++r) {
        float s = val[0][r] + val[1][r] + val[2][r] + val[3][r];
        float q = val[0][r] * val[0][r] + val[1][r] * val[1][r] +
                  val[2][r] * val[2][r] + val[3][r] * val[3][r];
#pragma unroll
        for (int off = 1; off <= 8; off <<= 1) {
          s += __shfl_xor(s, off);
          q += __shfl_xor(q, off);
        }
        const float mean = s * (1.f / 64.f);
        const float var  = q * (1.f / 64.f) - mean * mean;
        const float rstd = rsqrtf(var + 1e-5f);
#pragma unroll
        for (int nt = 0; nt < 4; ++nt) {
          const int col = nt * 16 + l15;
          const float gg = g_ln2g[col], bb = g_ln2b[col];
          const float xn = (val[nt][r] - mean) * rstd * gg + bb;
          if (mt == 0) pool[nt][r] = 0.5f * xn;
          else         pool[nt][r] += 0.5f * xn;
        }
      }
    }
#pragma unroll
    for (int nt = 0; nt < 4; ++nt)
#pragma unroll
      for (int r = 0; r < 4; ++r)
        pw[2304 + (quad * 4 + r) * 72 + nt * 16 + l15] = f2h(pool[nt][r]);

    // S6: head
    h8 pa[2];
#pragma unroll
    for (int ks = 0; ks < 2; ++ks)
      pa[ks] = *(const h8*)(pw + 2304 + l15 * 72 + ks * 32 + quad * 8);
    float part[4] = {0.f, 0.f, 0.f, 0.f};
#pragma unroll
    for (int nt = 0; nt < 2; ++nt) {
      const h8 bf0 = *(const h8*)(sm + 16384 + ((0 * 2 + nt) * 64 + lane) * 8);
      const h8 bf1 = *(const h8*)(sm + 16384 + ((1 * 2 + nt) * 64 + lane) * 8);
      f4 acc = {0.f, 0.f, 0.f, 0.f};
      acc = __builtin_amdgcn_mfma_f32_16x16x32_f16(pa[0], bf0, acc, 0, 0, 0);
      acc = __builtin_amdgcn_mfma_f32_16x16x32_f16(pa[1], bf1, acc, 0, 0, 0);
      const int col = nt * 16 + l15;
      const float bias = g_b3[col];
      const float w4v  = g_W4[col];
#pragma unroll
      for (int r = 0; r < 4; ++r) {
        float y = acc[r] + bias;
        y = y > 0.f ? y : 0.f;
        part[r] += y * w4v;
      }
    }
#pragma unroll
    for (int off = 1; off <= 8; off <<= 1)
#pragma unroll
      for (int r = 0; r < 4; ++r)
        part[r] += __shfl_xor(part[r], off);
    const float b4v = g_b4[0];
    if (l15 == 0) {
#pragma unroll
      for (int r = 0; r < 4; ++r)
        g_out[m0 + quad * 4 + r] = part[r] + b4v;
    }
  }
}

extern "C" void kernel_launch(void* const* d_in, const int* in_sizes, int n_in,
                              void* d_out, int out_size, void* d_ws, size_t ws_size,
                              hipStream_t stream) {
  (void)in_sizes; (void)n_in; (void)out_size; (void)ws_size;
  unsigned short* ws = (unsigned short*)d_ws;

  k_pre<<<1, 256, 0, stream>>>(
      (const float*)d_in[3], (const float*)d_in[4], (const float*)d_in[6],
      (const float*)d_in[10], (const float*)d_in[12], (const float*)d_in[16],
      ws);

  k_enc<<<512, 256, 0, stream>>>(
      (const int*)d_in[1], (const int*)d_in[2],
      (const float*)d_in[5], (const float*)d_in[7],
      (const float*)d_in[8], (const float*)d_in[9],
      ws, ws + WF_ARCH);

  k_attn<<<1024, 128, 0, stream>>>(
      (const int*)d_in[0],
      (const float*)d_in[3],
      (const float*)d_in[11], (const float*)d_in[13],
      (const float*)d_in[14], (const float*)d_in[15],
      (const float*)d_in[17], (const float*)d_in[18],
      (const float*)d_in[19],
      ws, (float*)d_out);
}